// Round 6
// baseline (299.718 us; speedup 1.0000x reference)
//
#include <hip/hip_runtime.h>
#include <math.h>

#define B_N    8192
#define D_DIM  192
#define C_CLS  1024
#define MARGIN 0.2f
#define EPS_T  1e-6f

#define TI     128
#define TJ     128
#define NIB    64            // B_N / TI
#define JSPLIT 16
#define JLEN   512           // B_N / JSPLIT
#define NTILE  4             // JLEN / TJ
#define LDB    200           // LDS j-tile row stride in bf16 (400 B; 0 conflicts measured R3/R5)
#define NBLK   1024          // NIB * JSPLIT
#define NTHR   256
#define POISON 0xAAAAAAAAu   // harness re-poisons d_ws to 0xAA; counters CAS-normalized

typedef short v8s __attribute__((ext_vector_type(8)));
typedef float v4f __attribute__((ext_vector_type(4)));

__device__ __forceinline__ unsigned fkey(float f) {
  unsigned u = __float_as_uint(f);
  return (u & 0x80000000u) ? ~u : (u | 0x80000000u);
}
__device__ __forceinline__ unsigned short to_bf(float x) {
  unsigned u = __float_as_uint(x);
  u += 0x7fffu + ((u >> 16) & 1u);
  return (unsigned short)(u >> 16);
}

// ---------------- prep: fp32->bf16 + sq ----------------
__global__ __launch_bounds__(NTHR) void prep_kernel(
    const float* __restrict__ e, unsigned short* __restrict__ ebf,
    float* __restrict__ sq) {
  int w = threadIdx.x >> 6, lane = threadIdx.x & 63;
  #pragma unroll
  for (int r = 0; r < 2; ++r) {
    int row = blockIdx.x * 8 + w * 2 + r;
    const float* p = e + (size_t)row * D_DIM;
    float v0 = p[lane], v1 = p[lane + 64], v2 = p[lane + 128];
    unsigned short* q = ebf + (size_t)row * D_DIM;
    q[lane] = to_bf(v0); q[lane + 64] = to_bf(v1); q[lane + 128] = to_bf(v2);
    float s = v0 * v0 + v1 * v1 + v2 * v2;
    #pragma unroll
    for (int off = 32; off; off >>= 1) s += __shfl_xor(s, off);
    if (lane == 0) sq[row] = s;
  }
}

// ---------------- mine (16x16x32, i-regs/j-LDS) + CE + finisher triplet ----------------
__global__ __launch_bounds__(NTHR, 3) void mine_kernel(
    const unsigned short* __restrict__ ebf, const int* __restrict__ tgt,
    const float* __restrict__ sq, const float* __restrict__ logits,
    const float* __restrict__ e,
    unsigned long long* __restrict__ posS, unsigned long long* __restrict__ negS,
    unsigned* __restrict__ tileCnt, float* __restrict__ accum,
    float* __restrict__ out) {
  // overlay: lds_b (mining) reused as lds_pos/lds_neg (finisher phase)
  __shared__ __align__(16) char sm[TJ * LDB * 2];   // 51200 B
  unsigned short* lds_b = (unsigned short*)sm;
  unsigned long long* lds_pos = (unsigned long long*)sm;          // [TI]
  unsigned long long* lds_neg = (unsigned long long*)(sm + 2048); // [TI]
  __shared__ int   lds_t[TJ];
  __shared__ float lds_s[TJ];
  __shared__ float red_a[4], red_b[4];
  __shared__ unsigned sflag;

  const int tid  = threadIdx.x;
  const int w    = tid >> 6;
  const int lane = tid & 63;
  const int ln15 = lane & 15;
  const int quad = lane >> 4;
  const int tile  = blockIdx.x & (NIB - 1);
  const int slice = blockIdx.x >> 6;
  const int i0 = tile * TI;
  const int jb = slice * JLEN;
  const float NINF = -__builtin_inff();
  const float PINF =  __builtin_inff();

  // i-side B fragments in registers (one-time, L2-hit): i = i0 + w*32 + isub*16 + ln15
  v8s bfrag[2][6];
  int myt[2];
  #pragma unroll
  for (int isub = 0; isub < 2; ++isub) {
    int row = i0 + w * 32 + isub * 16 + ln15;
    const unsigned short* bp = ebf + (size_t)row * D_DIM + quad * 8;
    #pragma unroll
    for (int ks = 0; ks < 6; ++ks) bfrag[isub][ks] = *(const v8s*)(bp + ks * 32);
    myt[isub] = tgt[row];
  }

  float pv[2] = {NINF, NINF}, nv[2] = {PINF, PINF};

  for (int jt = 0; jt < NTILE; ++jt) {
    const int j0 = jb + jt * TJ;
    __syncthreads();
    // stage j-tile: 128 rows x 192 bf16 = 3072 16B chunks, 12 per thread
    #pragma unroll
    for (int t = 0; t < 12; ++t) {
      int c = t * NTHR + tid;
      int row = c / 24;
      int off = c - row * 24;
      *(v8s*)&lds_b[row * LDB + off * 8] =
          *(const v8s*)(ebf + (size_t)(j0 + row) * D_DIM + off * 8);
    }
    if (tid < TJ) { lds_t[tid] = tgt[j0 + tid]; lds_s[tid] = sq[j0 + tid]; }
    __syncthreads();

    for (int jc = 0; jc < TJ / 16; ++jc) {
      // A-frags (j-side) from LDS: row jc*16+ln15, col ks*32+quad*8
      v8s af[6];
      #pragma unroll
      for (int ks = 0; ks < 6; ++ks)
        af[ks] = *(const v8s*)&lds_b[(jc * 16 + ln15) * LDB + ks * 32 + quad * 8];
      v4f acc0 = (v4f){0.f, 0.f, 0.f, 0.f};
      v4f acc1 = (v4f){0.f, 0.f, 0.f, 0.f};
      #pragma unroll
      for (int ks = 0; ks < 6; ++ks) {
        acc0 = __builtin_amdgcn_mfma_f32_16x16x32_bf16(af[ks], bfrag[0][ks], acc0, 0, 0, 0);
        acc1 = __builtin_amdgcn_mfma_f32_16x16x32_bf16(af[ks], bfrag[1][ks], acc1, 0, 0, 0);
      }
      // C/D: col = i = ln15 band; row = j = jc*16 + quad*4 + r
      float4 s4 = *(const float4*)&lds_s[jc * 16 + quad * 4];   // wave-broadcast
      int4   t4 = *(const int4*)&lds_t[jc * 16 + quad * 4];
      const unsigned cbase = ((unsigned)jt << 5) | ((unsigned)jc << 2);
      #pragma unroll
      for (int r = 0; r < 4; ++r) {
        float sv = (r == 0) ? s4.x : (r == 1) ? s4.y : (r == 2) ? s4.z : s4.w;
        int   tv = (r == 0) ? t4.x : (r == 1) ? t4.y : (r == 2) ? t4.z : t4.w;
        unsigned cc = cbase | (unsigned)r;
        {
          float val = fmaf(acc0[r], -2.0f, sv);
          float key = __uint_as_float((__float_as_uint(val) & 0xFFFFFF80u) | cc);
          bool same = (tv == myt[0]);
          pv[0] = fmaxf(pv[0], same ? key : NINF);
          nv[0] = fminf(nv[0], same ? PINF : key);
        }
        {
          float val = fmaf(acc1[r], -2.0f, sv);
          float key = __uint_as_float((__float_as_uint(val) & 0xFFFFFF80u) | cc);
          bool same = (tv == myt[1]);
          pv[1] = fmaxf(pv[1], same ? key : NINF);
          nv[1] = fminf(nv[1], same ? PINF : key);
        }
      }
    }
  }

  // decode (per-lane quad!), reduce across quads, publish per-slice (plain stores, no init)
  #pragma unroll
  for (int isub = 0; isub < 2; ++isub) {
    unsigned long long pk = 0ULL, nk = ~0ULL;
    if (pv[isub] != NINF) {
      unsigned c = __float_as_uint(pv[isub]) & 127u;
      unsigned jr = (unsigned)jb + ((c >> 5) & 3u) * TJ + ((c >> 2) & 7u) * 16u +
                    (unsigned)quad * 4u + (c & 3u);
      pk = ((unsigned long long)fkey(pv[isub]) << 32) | (unsigned long long)(~jr);
    }
    if (nv[isub] != PINF) {
      unsigned c = __float_as_uint(nv[isub]) & 127u;
      unsigned jr = (unsigned)jb + ((c >> 5) & 3u) * TJ + ((c >> 2) & 7u) * 16u +
                    (unsigned)quad * 4u + (c & 3u);
      nk = ((unsigned long long)fkey(nv[isub]) << 32) | (unsigned long long)jr;
    }
    unsigned long long t;
    t = __shfl_xor(pk, 16); pk = pk > t ? pk : t;
    t = __shfl_xor(pk, 32); pk = pk > t ? pk : t;
    t = __shfl_xor(nk, 16); nk = nk < t ? nk : t;
    t = __shfl_xor(nk, 32); nk = nk < t ? nk : t;
    if (quad == 0) {
      int il = w * 32 + isub * 16 + ln15;
      __hip_atomic_store(&posS[(size_t)slice * B_N + i0 + il], pk,
                         __ATOMIC_RELAXED, __HIP_MEMORY_SCOPE_AGENT);
      __hip_atomic_store(&negS[(size_t)slice * B_N + i0 + il], nk,
                         __ATOMIC_RELAXED, __HIP_MEMORY_SCOPE_AGENT);
    }
  }
  __threadfence();
  __syncthreads();
  if (tid == 0) {
    atomicCAS(&tileCnt[tile], 0u, POISON);   // normalize 0-or-poison init
    unsigned old = atomicAdd(&tileCnt[tile], 1u);
    sflag = (old == POISON + (JSPLIT - 1)) ? 1u : 0u;
  }

  // ---- fused cross-entropy: 8 logits rows per block ----
  float ce_acc = 0.f;
  #pragma unroll
  for (int it = 0; it < 2; ++it) {
    int row = blockIdx.x * 8 + it * 4 + w;
    const float* lp = logits + (size_t)row * C_CLS;
    float4 x[4];
    #pragma unroll
    for (int t = 0; t < 4; ++t) x[t] = *(const float4*)(lp + lane * 4 + 256 * t);
    float m = NINF;
    #pragma unroll
    for (int t = 0; t < 4; ++t)
      m = fmaxf(m, fmaxf(fmaxf(x[t].x, x[t].y), fmaxf(x[t].z, x[t].w)));
    #pragma unroll
    for (int off = 32; off; off >>= 1) m = fmaxf(m, __shfl_xor(m, off));
    float s = 0.f;
    #pragma unroll
    for (int t = 0; t < 4; ++t)
      s += __expf(x[t].x - m) + __expf(x[t].y - m) +
           __expf(x[t].z - m) + __expf(x[t].w - m);
    #pragma unroll
    for (int off = 32; off; off >>= 1) s += __shfl_xor(s, off);
    if (lane == 0) ce_acc += m + __logf(s) - lp[tgt[row]];
  }
  if (lane == 0) red_a[w] = ce_acc;
  __syncthreads();
  if (tid == 0) atomicAdd(&accum[0], red_a[0] + red_a[1] + red_a[2] + red_a[3]);
  __syncthreads();   // publish sflag, protect red_a reuse

  // ---- last finisher of this i-tile: merge JSPLIT slices, exact fp32 triplet ----
  if (sflag) {
    __threadfence();
    if (tid < TI) {
      unsigned long long P = 0ULL, Nn = ~0ULL;
      for (int s = 0; s < JSPLIT; ++s) {
        unsigned long long a = __hip_atomic_load(&posS[(size_t)s * B_N + i0 + tid],
                                                 __ATOMIC_RELAXED, __HIP_MEMORY_SCOPE_AGENT);
        unsigned long long b = __hip_atomic_load(&negS[(size_t)s * B_N + i0 + tid],
                                                 __ATOMIC_RELAXED, __HIP_MEMORY_SCOPE_AGENT);
        P = a > P ? a : P;
        Nn = b < Nn ? b : Nn;
      }
      lds_pos[tid] = P; lds_neg[tid] = Nn;   // overlay region: lds_b is dead now
    }
    __syncthreads();
    float tsum = 0.f, tcnt = 0.f;
    for (int rr = 0; rr < 32; ++rr) {
      int il = w * 32 + rr;
      int i  = i0 + il;
      unsigned long long pp = lds_pos[il], np = lds_neg[il];
      unsigned pidx = ~(unsigned)pp;
      unsigned nidx = (unsigned)np;
      bool valid = (pp != 0ULL) && (np != ~0ULL) && (pidx != (unsigned)i);
      float dap = 0.f, dan = 0.f;
      if (valid && lane < 48) {
        float4 a4 = *(const float4*)(e + (size_t)i    * D_DIM + lane * 4);
        float4 p4 = *(const float4*)(e + (size_t)pidx * D_DIM + lane * 4);
        float4 n4 = *(const float4*)(e + (size_t)nidx * D_DIM + lane * 4);
        float d;
        d = a4.x - p4.x + EPS_T; dap += d * d;
        d = a4.y - p4.y + EPS_T; dap += d * d;
        d = a4.z - p4.z + EPS_T; dap += d * d;
        d = a4.w - p4.w + EPS_T; dap += d * d;
        d = a4.x - n4.x + EPS_T; dan += d * d;
        d = a4.y - n4.y + EPS_T; dan += d * d;
        d = a4.z - n4.z + EPS_T; dan += d * d;
        d = a4.w - n4.w + EPS_T; dan += d * d;
      }
      #pragma unroll
      for (int off = 32; off; off >>= 1) {
        dap += __shfl_xor(dap, off);
        dan += __shfl_xor(dan, off);
      }
      if (lane == 0 && valid) {
        tsum += fmaxf(sqrtf(dap) - sqrtf(dan) + MARGIN, 0.f);
        tcnt += 1.f;
      }
    }
    if (lane == 0) { red_a[w] = tsum; red_b[w] = tcnt; }
    __syncthreads();
    if (tid == 0) {
      atomicAdd(&accum[1], red_a[0] + red_a[1] + red_a[2] + red_a[3]);
      atomicAdd(&accum[2], red_b[0] + red_b[1] + red_b[2] + red_b[3]);
    }
  }

  // ---- global finalize: last of NBLK blocks writes out ----
  __threadfence();
  __syncthreads();
  if (tid == 0) {
    unsigned* gcnt = (unsigned*)&accum[3];
    atomicCAS(gcnt, 0u, POISON);
    unsigned old = atomicAdd(gcnt, 1u);
    if (old == POISON + (NBLK - 1)) {
      __threadfence();
      float cls = __hip_atomic_load(&accum[0], __ATOMIC_RELAXED, __HIP_MEMORY_SCOPE_AGENT);
      float ts  = __hip_atomic_load(&accum[1], __ATOMIC_RELAXED, __HIP_MEMORY_SCOPE_AGENT);
      float tc  = __hip_atomic_load(&accum[2], __ATOMIC_RELAXED, __HIP_MEMORY_SCOPE_AGENT);
      float trip = (tc > 0.f) ? ts / fmaxf(tc, 1.f) : 0.f;
      out[0] = cls / (float)B_N + trip;
    }
  }
}

extern "C" void kernel_launch(void* const* d_in, const int* in_sizes, int n_in,
                              void* d_out, int out_size, void* d_ws, size_t ws_size,
                              hipStream_t stream) {
  const float* emb    = (const float*)d_in[0];
  const float* logits = (const float*)d_in[1];
  const int*   tgt    = (const int*)d_in[2];
  float* out = (float*)d_out;

  char* ws = (char*)d_ws;
  unsigned short* ebf = (unsigned short*)ws;                        // 3,145,728 B
  float* sq = (float*)(ws + 3145728);                               // 32,768 B
  unsigned long long* posS = (unsigned long long*)(ws + 3178496);   // 1,048,576 B
  unsigned long long* negS = (unsigned long long*)(ws + 4227072);   // 1,048,576 B
  unsigned* tileCnt = (unsigned*)(ws + 5275648);                    // 256 B
  float* accum = (float*)(ws + 5275904);                            // 16 B: cls,tsum,tcnt,counter

  prep_kernel<<<NBLK, NTHR, 0, stream>>>(emb, ebf, sq);
  mine_kernel<<<NBLK, NTHR, 0, stream>>>(ebf, tgt, sq, logits, emb,
                                         posS, negS, tileCnt, accum, out);
}

// Round 7
// 219.655 us; speedup vs baseline: 1.3645x; 1.3645x over previous
//
#include <hip/hip_runtime.h>
#include <math.h>

#define B_N    8192
#define D_DIM  192
#define C_CLS  1024
#define MARGIN 0.2f
#define EPS_T  1e-6f

#define TI     128
#define TJ     128
#define NIB    64            // B_N / TI
#define JSPLIT 8
#define JLEN   1024          // B_N / JSPLIT
#define NTILE  8             // JLEN / TJ
#define LDB    200           // LDS row stride in bf16 (R3-proven: 0 bank conflicts)
#define NBLK   512           // NIB * JSPLIT
#define NTHR   256
#define POISON 0xAAAAAAAAu   // harness re-poisons d_ws to 0xAA; counters CAS-normalized

typedef short v8s  __attribute__((ext_vector_type(8)));
typedef float v16f __attribute__((ext_vector_type(16)));

__device__ __forceinline__ unsigned fkey(float f) {
  unsigned u = __float_as_uint(f);
  return (u & 0x80000000u) ? ~u : (u | 0x80000000u);
}
__device__ __forceinline__ unsigned short to_bf(float x) {
  unsigned u = __float_as_uint(x);
  u += 0x7fffu + ((u >> 16) & 1u);
  return (unsigned short)(u >> 16);
}

// ---------------- prep: fp32->bf16 + sq ----------------
__global__ __launch_bounds__(NTHR) void prep_kernel(
    const float* __restrict__ e, unsigned short* __restrict__ ebf,
    float* __restrict__ sq) {
  int w = threadIdx.x >> 6, lane = threadIdx.x & 63;
  #pragma unroll
  for (int r = 0; r < 4; ++r) {
    int row = blockIdx.x * 16 + w * 4 + r;
    const float* p = e + (size_t)row * D_DIM;
    float v0 = p[lane], v1 = p[lane + 64], v2 = p[lane + 128];
    unsigned short* q = ebf + (size_t)row * D_DIM;
    q[lane] = to_bf(v0); q[lane + 64] = to_bf(v1); q[lane + 128] = to_bf(v2);
    float s = v0 * v0 + v1 * v1 + v2 * v2;
    #pragma unroll
    for (int off = 32; off; off >>= 1) s += __shfl_xor(s, off);
    if (lane == 0) sq[row] = s;
  }
}

// ------- mine (R3 core) + CE + last-finisher triplet + finalize -------
__global__ __launch_bounds__(NTHR, 2) void mine_kernel(
    const unsigned short* __restrict__ ebf, const int* __restrict__ tgt,
    const float* __restrict__ sq, const float* __restrict__ logits,
    const float* __restrict__ e,
    unsigned long long* __restrict__ posS, unsigned long long* __restrict__ negS,
    unsigned* __restrict__ tileCnt, float* __restrict__ accum,
    float* __restrict__ out) {
  // overlay: mining j-tile buffer reused as merge arrays after the j-loop
  __shared__ __align__(16) char sm[TJ * LDB * 2];   // 51200 B
  unsigned short* lds_b = (unsigned short*)sm;
  unsigned long long* lds_pos = (unsigned long long*)sm;          // [TI]
  unsigned long long* lds_neg = (unsigned long long*)(sm + 1024); // [TI]
  __shared__ int   lds_t[TJ];
  __shared__ float lds_s[TJ];
  __shared__ float red_a[4], red_b[4];
  __shared__ unsigned sflag;

  const int tid  = threadIdx.x;
  const int w    = tid >> 6;
  const int lane = tid & 63;
  const int n5   = lane & 31;
  const int h    = lane >> 5;
  const int wj   = w & 1;          // j half (M side)
  const int wi   = w >> 1;         // i half (N side)
  const int tile  = blockIdx.x & (NIB - 1);
  const int slice = blockIdx.x >> 6;
  const int i0 = tile * TI;
  const int jb = slice * JLEN;
  const float NINF = -__builtin_inff();
  const float PINF =  __builtin_inff();

  // ---- stage i-tile through LDS (coalesced), pull B-frags to regs (R3) ----
  {
    const unsigned short* src = ebf + (size_t)i0 * D_DIM;
    #pragma unroll
    for (int t = 0; t < 12; ++t) {
      int c = t * NTHR + tid;
      int row = c / 24;
      int off = c - row * 24;
      *(v8s*)&lds_b[row * LDB + off * 8] =
          *(const v8s*)(src + (size_t)row * D_DIM + off * 8);
    }
  }
  __syncthreads();
  v8s bfrag[2][12];
  int my_t[2];
  #pragma unroll
  for (int tb = 0; tb < 2; ++tb) {
    #pragma unroll
    for (int kc = 0; kc < 12; ++kc)
      bfrag[tb][kc] = *(const v8s*)&lds_b[(wi * 64 + tb * 32 + n5) * LDB + kc * 16 + h * 8];
    my_t[tb] = tgt[i0 + wi * 64 + tb * 32 + n5];
  }

  float pv[2] = {NINF, NINF}, nv[2] = {PINF, PINF};

  for (int jt = 0; jt < NTILE; ++jt) {
    const int j0 = jb + jt * TJ;
    __syncthreads();
    #pragma unroll
    for (int t = 0; t < 12; ++t) {
      int c = t * NTHR + tid;
      int row = c / 24;
      int off = c - row * 24;
      *(v8s*)&lds_b[row * LDB + off * 8] =
          *(const v8s*)(ebf + (size_t)(j0 + row) * D_DIM + off * 8);
    }
    if (tid < TJ) { lds_t[tid] = tgt[j0 + tid]; lds_s[tid] = sq[j0 + tid]; }
    __syncthreads();

    v16f acc[2][2];
    #pragma unroll
    for (int ta = 0; ta < 2; ++ta)
      #pragma unroll
      for (int tb = 0; tb < 2; ++tb)
        #pragma unroll
        for (int r = 0; r < 16; ++r) acc[ta][tb][r] = 0.f;

    #pragma unroll
    for (int kc = 0; kc < 12; ++kc) {
      v8s afr0 = *(const v8s*)&lds_b[(wj * 64 +  0 + n5) * LDB + kc * 16 + h * 8];
      v8s afr1 = *(const v8s*)&lds_b[(wj * 64 + 32 + n5) * LDB + kc * 16 + h * 8];
      acc[0][0] = __builtin_amdgcn_mfma_f32_32x32x16_bf16(afr0, bfrag[0][kc], acc[0][0], 0, 0, 0);
      acc[0][1] = __builtin_amdgcn_mfma_f32_32x32x16_bf16(afr0, bfrag[1][kc], acc[0][1], 0, 0, 0);
      acc[1][0] = __builtin_amdgcn_mfma_f32_32x32x16_bf16(afr1, bfrag[0][kc], acc[1][0], 0, 0, 0);
      acc[1][1] = __builtin_amdgcn_mfma_f32_32x32x16_bf16(afr1, bfrag[1][kc], acc[1][1], 0, 0, 0);
    }

    // epilogue: j = jb + jt*128 + wj*64 + ta*32 + p*8 + h*4 + q ; i = col
    // 8-bit code (jt|ta|p|q) in low mantissa -> branchless float min/max (R5-proven)
    const unsigned cb = (unsigned)jt << 5;
    #pragma unroll
    for (int ta = 0; ta < 2; ++ta) {
      #pragma unroll
      for (int p = 0; p < 4; ++p) {
        int jb4 = wj * 64 + ta * 32 + p * 8 + h * 4;
        float4 s4 = *(const float4*)&lds_s[jb4];   // wave-broadcast
        int4   t4 = *(const int4*)&lds_t[jb4];
        #pragma unroll
        for (int q = 0; q < 4; ++q) {
          float sv = (q == 0) ? s4.x : (q == 1) ? s4.y : (q == 2) ? s4.z : s4.w;
          int   tv = (q == 0) ? t4.x : (q == 1) ? t4.y : (q == 2) ? t4.z : t4.w;
          unsigned cc = cb | (unsigned)(ta * 16 + p * 4 + q);
          #pragma unroll
          for (int tb = 0; tb < 2; ++tb) {
            float val = fmaf(acc[ta][tb][p * 4 + q], -2.0f, sv);
            float key = __uint_as_float((__float_as_uint(val) & 0xFFFFFF00u) | cc);
            bool same = (tv == my_t[tb]);
            pv[tb] = fmaxf(pv[tb], same ? key : NINF);
            nv[tb] = fminf(nv[tb], same ? PINF : key);
          }
        }
      }
    }
  }

  // ---- decode, merge h-partners, LDS-merge across wj waves, publish slice ----
  __syncthreads();   // all waves done reading lds_b
  if (tid < TI) { lds_pos[tid] = 0ULL; lds_neg[tid] = ~0ULL; }
  __syncthreads();
  #pragma unroll
  for (int tb = 0; tb < 2; ++tb) {
    unsigned long long pk = 0ULL, nk = ~0ULL;
    if (pv[tb] != NINF) {
      unsigned c = __float_as_uint(pv[tb]) & 255u;
      unsigned jr = (unsigned)jb + ((c >> 5) & 7u) * 128u + (unsigned)wj * 64u +
                    ((c >> 4) & 1u) * 32u + ((c >> 2) & 3u) * 8u + (unsigned)h * 4u + (c & 3u);
      pk = ((unsigned long long)fkey(pv[tb]) << 32) | (unsigned long long)(~jr);
    }
    if (nv[tb] != PINF) {
      unsigned c = __float_as_uint(nv[tb]) & 255u;
      unsigned jr = (unsigned)jb + ((c >> 5) & 7u) * 128u + (unsigned)wj * 64u +
                    ((c >> 4) & 1u) * 32u + ((c >> 2) & 3u) * 8u + (unsigned)h * 4u + (c & 3u);
      nk = ((unsigned long long)fkey(nv[tb]) << 32) | (unsigned long long)jr;
    }
    unsigned long long po = __shfl_xor(pk, 32);
    unsigned long long no = __shfl_xor(nk, 32);
    pk = pk > po ? pk : po;
    nk = nk < no ? nk : no;
    if (h == 0) {
      int il = wi * 64 + tb * 32 + n5;
      if (pk != 0ULL)  atomicMax(&lds_pos[il], pk);
      if (nk != ~0ULL) atomicMin(&lds_neg[il], nk);
    }
  }
  __syncthreads();
  if (tid < TI) {
    __hip_atomic_store(&posS[(size_t)slice * B_N + i0 + tid], lds_pos[tid],
                       __ATOMIC_RELAXED, __HIP_MEMORY_SCOPE_AGENT);
    __hip_atomic_store(&negS[(size_t)slice * B_N + i0 + tid], lds_neg[tid],
                       __ATOMIC_RELAXED, __HIP_MEMORY_SCOPE_AGENT);
  }
  __threadfence();
  __syncthreads();
  if (tid == 0) {
    atomicCAS(&tileCnt[tile], 0u, POISON);   // normalize 0-or-poison init
    unsigned old = atomicAdd(&tileCnt[tile], 1u);
    sflag = (old == POISON + (JSPLIT - 1)) ? 1u : 0u;
  }

  // ---- fused cross-entropy: 16 logits rows per block ----
  float ce_acc = 0.f;
  #pragma unroll
  for (int it = 0; it < 4; ++it) {
    int row = blockIdx.x * 16 + it * 4 + w;
    const float* lp = logits + (size_t)row * C_CLS;
    float4 x[4];
    #pragma unroll
    for (int t = 0; t < 4; ++t) x[t] = *(const float4*)(lp + lane * 4 + 256 * t);
    float m = NINF;
    #pragma unroll
    for (int t = 0; t < 4; ++t)
      m = fmaxf(m, fmaxf(fmaxf(x[t].x, x[t].y), fmaxf(x[t].z, x[t].w)));
    #pragma unroll
    for (int off = 32; off; off >>= 1) m = fmaxf(m, __shfl_xor(m, off));
    float s = 0.f;
    #pragma unroll
    for (int t = 0; t < 4; ++t)
      s += __expf(x[t].x - m) + __expf(x[t].y - m) +
           __expf(x[t].z - m) + __expf(x[t].w - m);
    #pragma unroll
    for (int off = 32; off; off >>= 1) s += __shfl_xor(s, off);
    if (lane == 0) ce_acc += m + __logf(s) - lp[tgt[row]];
  }
  if (lane == 0) red_a[w] = ce_acc;
  __syncthreads();
  if (tid == 0) atomicAdd(&accum[0], red_a[0] + red_a[1] + red_a[2] + red_a[3]);
  __syncthreads();   // publish sflag, protect red_a reuse

  // ---- last finisher of this i-tile: merge JSPLIT slices, exact fp32 triplet ----
  if (sflag) {
    __threadfence();
    if (tid < TI) {
      unsigned long long P = 0ULL, Nn = ~0ULL;
      for (int s = 0; s < JSPLIT; ++s) {
        unsigned long long a = __hip_atomic_load(&posS[(size_t)s * B_N + i0 + tid],
                                                 __ATOMIC_RELAXED, __HIP_MEMORY_SCOPE_AGENT);
        unsigned long long b = __hip_atomic_load(&negS[(size_t)s * B_N + i0 + tid],
                                                 __ATOMIC_RELAXED, __HIP_MEMORY_SCOPE_AGENT);
        P = a > P ? a : P;
        Nn = b < Nn ? b : Nn;
      }
      lds_pos[tid] = P; lds_neg[tid] = Nn;
    }
    __syncthreads();
    float tsum = 0.f, tcnt = 0.f;
    for (int rr = 0; rr < 32; ++rr) {
      int il = w * 32 + rr;
      int i  = i0 + il;
      unsigned long long pp = lds_pos[il], np = lds_neg[il];
      unsigned pidx = ~(unsigned)pp;
      unsigned nidx = (unsigned)np;
      bool valid = (pp != 0ULL) && (np != ~0ULL) && (pidx != (unsigned)i);
      float dap = 0.f, dan = 0.f;
      if (valid && lane < 48) {
        float4 a4 = *(const float4*)(e + (size_t)i    * D_DIM + lane * 4);
        float4 p4 = *(const float4*)(e + (size_t)pidx * D_DIM + lane * 4);
        float4 n4 = *(const float4*)(e + (size_t)nidx * D_DIM + lane * 4);
        float d;
        d = a4.x - p4.x + EPS_T; dap += d * d;
        d = a4.y - p4.y + EPS_T; dap += d * d;
        d = a4.z - p4.z + EPS_T; dap += d * d;
        d = a4.w - p4.w + EPS_T; dap += d * d;
        d = a4.x - n4.x + EPS_T; dan += d * d;
        d = a4.y - n4.y + EPS_T; dan += d * d;
        d = a4.z - n4.z + EPS_T; dan += d * d;
        d = a4.w - n4.w + EPS_T; dan += d * d;
      }
      #pragma unroll
      for (int off = 32; off; off >>= 1) {
        dap += __shfl_xor(dap, off);
        dan += __shfl_xor(dan, off);
      }
      if (lane == 0 && valid) {
        tsum += fmaxf(sqrtf(dap) - sqrtf(dan) + MARGIN, 0.f);
        tcnt += 1.f;
      }
    }
    if (lane == 0) { red_a[w] = tsum; red_b[w] = tcnt; }
    __syncthreads();
    if (tid == 0) {
      atomicAdd(&accum[1], red_a[0] + red_a[1] + red_a[2] + red_a[3]);
      atomicAdd(&accum[2], red_b[0] + red_b[1] + red_b[2] + red_b[3]);
    }
  }

  // ---- global finalize: last of NBLK blocks writes out ----
  __threadfence();
  __syncthreads();
  if (tid == 0) {
    unsigned* gcnt = (unsigned*)&accum[3];
    atomicCAS(gcnt, 0u, POISON);
    unsigned old = atomicAdd(gcnt, 1u);
    if (old == POISON + (NBLK - 1)) {
      __threadfence();
      float cls = __hip_atomic_load(&accum[0], __ATOMIC_RELAXED, __HIP_MEMORY_SCOPE_AGENT);
      float ts  = __hip_atomic_load(&accum[1], __ATOMIC_RELAXED, __HIP_MEMORY_SCOPE_AGENT);
      float tc  = __hip_atomic_load(&accum[2], __ATOMIC_RELAXED, __HIP_MEMORY_SCOPE_AGENT);
      float trip = (tc > 0.f) ? ts / fmaxf(tc, 1.f) : 0.f;
      out[0] = cls / (float)B_N + trip;
    }
  }
}

extern "C" void kernel_launch(void* const* d_in, const int* in_sizes, int n_in,
                              void* d_out, int out_size, void* d_ws, size_t ws_size,
                              hipStream_t stream) {
  const float* emb    = (const float*)d_in[0];
  const float* logits = (const float*)d_in[1];
  const int*   tgt    = (const int*)d_in[2];
  float* out = (float*)d_out;

  char* ws = (char*)d_ws;
  unsigned short* ebf = (unsigned short*)ws;                        // 3,145,728 B
  float* sq = (float*)(ws + 3145728);                               // 32,768 B
  unsigned long long* posS = (unsigned long long*)(ws + 3178496);   // 524,288 B
  unsigned long long* negS = (unsigned long long*)(ws + 3702784);   // 524,288 B
  unsigned* tileCnt = (unsigned*)(ws + 4227072);                    // 256 B
  float* accum = (float*)(ws + 4227328);                            // 16 B: cls,tsum,tcnt,counter

  prep_kernel<<<NBLK, NTHR, 0, stream>>>(emb, ebf, sq);
  mine_kernel<<<NBLK, NTHR, 0, stream>>>(ebf, tgt, sq, logits, emb,
                                         posS, negS, tileCnt, accum, out);
}

// Round 8
// 160.408 us; speedup vs baseline: 1.8685x; 1.3694x over previous
//
#include <hip/hip_runtime.h>
#include <math.h>

#define B_N    8192
#define D_DIM  192
#define C_CLS  1024
#define MARGIN 0.2f
#define EPS_T  1e-6f

#define TI     128
#define TJ     128
#define NIB    64            // B_N / TI
#define JSPLIT 8
#define JLEN   1024          // B_N / JSPLIT
#define NTILE  8             // JLEN / TJ
#define LDB    200           // LDS row stride in bf16 (R3-proven: 0 bank conflicts)
#define NBLK   512           // NIB * JSPLIT
#define NTHR   256

typedef short v8s  __attribute__((ext_vector_type(8)));
typedef float v16f __attribute__((ext_vector_type(16)));

__device__ __forceinline__ unsigned fkey(float f) {
  unsigned u = __float_as_uint(f);
  return (u & 0x80000000u) ? ~u : (u | 0x80000000u);
}
__device__ __forceinline__ unsigned short to_bf(float x) {
  unsigned u = __float_as_uint(x);
  u += 0x7fffu + ((u >> 16) & 1u);
  return (unsigned short)(u >> 16);
}

// ---------------- prep: fp32->bf16 + sq + init (replaces memsets) ----------------
__global__ __launch_bounds__(NTHR) void prep_kernel(
    const float* __restrict__ e, unsigned short* __restrict__ ebf,
    float* __restrict__ sq,
    unsigned long long* __restrict__ posw, unsigned long long* __restrict__ negw,
    unsigned* __restrict__ tileCnt, float* __restrict__ accum) {
  int w = threadIdx.x >> 6, lane = threadIdx.x & 63;
  #pragma unroll
  for (int r = 0; r < 4; ++r) {
    int row = blockIdx.x * 16 + w * 4 + r;
    const float* p = e + (size_t)row * D_DIM;
    float v0 = p[lane], v1 = p[lane + 64], v2 = p[lane + 128];
    unsigned short* q = ebf + (size_t)row * D_DIM;
    q[lane] = to_bf(v0); q[lane + 64] = to_bf(v1); q[lane + 128] = to_bf(v2);
    float s = v0 * v0 + v1 * v1 + v2 * v2;
    #pragma unroll
    for (int off = 32; off; off >>= 1) s += __shfl_xor(s, off);
    if (lane == 0) sq[row] = s;
  }
  int tid = threadIdx.x;
  if (tid < 16)       posw[blockIdx.x * 16 + tid] = 0ULL;
  else if (tid < 32)  negw[blockIdx.x * 16 + (tid - 16)] = ~0ULL;
  if (blockIdx.x == 0) {
    if (tid >= 32 && tid < 96)  tileCnt[tid - 32] = 0u;
    if (tid >= 96 && tid < 100) ((unsigned*)accum)[tid - 96] = 0u;
  }
}

// ------- mine (R3 core) + CE + last-finisher triplet + finalize (NO fences) -------
__global__ __launch_bounds__(NTHR, 2) void mine_kernel(
    const unsigned short* __restrict__ ebf, const int* __restrict__ tgt,
    const float* __restrict__ sq, const float* __restrict__ logits,
    const float* __restrict__ e,
    unsigned long long* __restrict__ posw, unsigned long long* __restrict__ negw,
    unsigned* __restrict__ tileCnt, float* __restrict__ accum,
    float* __restrict__ out) {
  // overlay: mining j-tile buffer reused as merge arrays after the j-loop
  __shared__ __align__(16) char sm[TJ * LDB * 2];   // 51200 B
  unsigned short* lds_b = (unsigned short*)sm;
  unsigned long long* lds_pos = (unsigned long long*)sm;          // [TI]
  unsigned long long* lds_neg = (unsigned long long*)(sm + 1024); // [TI]
  __shared__ int   lds_t[TJ];
  __shared__ float lds_s[TJ];
  __shared__ float red_a[4], red_b[4];
  __shared__ unsigned sflag;

  const int tid  = threadIdx.x;
  const int w    = tid >> 6;
  const int lane = tid & 63;
  const int n5   = lane & 31;
  const int h    = lane >> 5;
  const int wj   = w & 1;          // j half (M side)
  const int wi   = w >> 1;         // i half (N side)
  const int tile  = blockIdx.x & (NIB - 1);
  const int slice = blockIdx.x >> 6;
  const int i0 = tile * TI;
  const int jb = slice * JLEN;
  const float NINF = -__builtin_inff();
  const float PINF =  __builtin_inff();

  // ---- stage i-tile through LDS (coalesced), pull B-frags to regs (R3) ----
  {
    const unsigned short* src = ebf + (size_t)i0 * D_DIM;
    #pragma unroll
    for (int t = 0; t < 12; ++t) {
      int c = t * NTHR + tid;
      int row = c / 24;
      int off = c - row * 24;
      *(v8s*)&lds_b[row * LDB + off * 8] =
          *(const v8s*)(src + (size_t)row * D_DIM + off * 8);
    }
  }
  __syncthreads();
  v8s bfrag[2][12];
  int my_t[2];
  #pragma unroll
  for (int tb = 0; tb < 2; ++tb) {
    #pragma unroll
    for (int kc = 0; kc < 12; ++kc)
      bfrag[tb][kc] = *(const v8s*)&lds_b[(wi * 64 + tb * 32 + n5) * LDB + kc * 16 + h * 8];
    my_t[tb] = tgt[i0 + wi * 64 + tb * 32 + n5];
  }

  float pv[2] = {NINF, NINF}, nv[2] = {PINF, PINF};

  #pragma unroll 1
  for (int jt = 0; jt < NTILE; ++jt) {
    const int j0 = jb + jt * TJ;
    __syncthreads();
    #pragma unroll
    for (int t = 0; t < 12; ++t) {
      int c = t * NTHR + tid;
      int row = c / 24;
      int off = c - row * 24;
      *(v8s*)&lds_b[row * LDB + off * 8] =
          *(const v8s*)(ebf + (size_t)(j0 + row) * D_DIM + off * 8);
    }
    if (tid < TJ) { lds_t[tid] = tgt[j0 + tid]; lds_s[tid] = sq[j0 + tid]; }
    __syncthreads();

    v16f acc[2][2];
    #pragma unroll
    for (int ta = 0; ta < 2; ++ta)
      #pragma unroll
      for (int tb = 0; tb < 2; ++tb)
        #pragma unroll
        for (int r = 0; r < 16; ++r) acc[ta][tb][r] = 0.f;

    #pragma unroll
    for (int kc = 0; kc < 12; ++kc) {
      v8s afr0 = *(const v8s*)&lds_b[(wj * 64 +  0 + n5) * LDB + kc * 16 + h * 8];
      v8s afr1 = *(const v8s*)&lds_b[(wj * 64 + 32 + n5) * LDB + kc * 16 + h * 8];
      acc[0][0] = __builtin_amdgcn_mfma_f32_32x32x16_bf16(afr0, bfrag[0][kc], acc[0][0], 0, 0, 0);
      acc[0][1] = __builtin_amdgcn_mfma_f32_32x32x16_bf16(afr0, bfrag[1][kc], acc[0][1], 0, 0, 0);
      acc[1][0] = __builtin_amdgcn_mfma_f32_32x32x16_bf16(afr1, bfrag[0][kc], acc[1][0], 0, 0, 0);
      acc[1][1] = __builtin_amdgcn_mfma_f32_32x32x16_bf16(afr1, bfrag[1][kc], acc[1][1], 0, 0, 0);
    }

    // epilogue: j = jb + jt*128 + wj*64 + ta*32 + p*8 + h*4 + q ; i = col
    const unsigned cb = (unsigned)jt << 5;
    #pragma unroll
    for (int ta = 0; ta < 2; ++ta) {
      #pragma unroll
      for (int p = 0; p < 4; ++p) {
        int jb4 = wj * 64 + ta * 32 + p * 8 + h * 4;
        float4 s4 = *(const float4*)&lds_s[jb4];   // wave-broadcast
        int4   t4 = *(const int4*)&lds_t[jb4];
        #pragma unroll
        for (int q = 0; q < 4; ++q) {
          float sv = (q == 0) ? s4.x : (q == 1) ? s4.y : (q == 2) ? s4.z : s4.w;
          int   tv = (q == 0) ? t4.x : (q == 1) ? t4.y : (q == 2) ? t4.z : t4.w;
          unsigned cc = cb | (unsigned)(ta * 16 + p * 4 + q);
          #pragma unroll
          for (int tb = 0; tb < 2; ++tb) {
            float val = fmaf(acc[ta][tb][p * 4 + q], -2.0f, sv);
            float key = __uint_as_float((__float_as_uint(val) & 0xFFFFFF00u) | cc);
            bool same = (tv == my_t[tb]);
            pv[tb] = fmaxf(pv[tb], same ? key : NINF);
            nv[tb] = fminf(nv[tb], same ? PINF : key);
          }
        }
      }
    }
  }

  // ---- decode, merge h-partners, LDS-merge across wj waves, global RMW merge ----
  __syncthreads();   // all waves done reading lds_b
  if (tid < TI) { lds_pos[tid] = 0ULL; lds_neg[tid] = ~0ULL; }
  __syncthreads();
  #pragma unroll
  for (int tb = 0; tb < 2; ++tb) {
    unsigned long long pk = 0ULL, nk = ~0ULL;
    if (pv[tb] != NINF) {
      unsigned c = __float_as_uint(pv[tb]) & 255u;
      unsigned jr = (unsigned)jb + ((c >> 5) & 7u) * 128u + (unsigned)wj * 64u +
                    ((c >> 4) & 1u) * 32u + ((c >> 2) & 3u) * 8u + (unsigned)h * 4u + (c & 3u);
      pk = ((unsigned long long)fkey(pv[tb]) << 32) | (unsigned long long)(~jr);
    }
    if (nv[tb] != PINF) {
      unsigned c = __float_as_uint(nv[tb]) & 255u;
      unsigned jr = (unsigned)jb + ((c >> 5) & 7u) * 128u + (unsigned)wj * 64u +
                    ((c >> 4) & 1u) * 32u + ((c >> 2) & 3u) * 8u + (unsigned)h * 4u + (c & 3u);
      nk = ((unsigned long long)fkey(nv[tb]) << 32) | (unsigned long long)jr;
    }
    unsigned long long po = __shfl_xor(pk, 32);
    unsigned long long no = __shfl_xor(nk, 32);
    pk = pk > po ? pk : po;
    nk = nk < no ? nk : no;
    if (h == 0) {
      int il = wi * 64 + tb * 32 + n5;
      if (pk != 0ULL)  atomicMax(&lds_pos[il], pk);
      if (nk != ~0ULL) atomicMin(&lds_neg[il], nk);
    }
  }
  __syncthreads();
  // device-scope RMWs: coherent at IC, no fence needed
  if (tid < TI) {
    atomicMax(&posw[i0 + tid], lds_pos[tid]);
    atomicMin(&negw[i0 + tid], lds_neg[tid]);
  }
  __syncthreads();   // emits s_waitcnt vmcnt(0): RMWs drained before elect
  if (tid == 0) {
    unsigned old = atomicAdd(&tileCnt[tile], 1u);
    sflag = (old == JSPLIT - 1) ? 1u : 0u;
  }

  // ---- fused cross-entropy: 16 logits rows per block ----
  float ce_acc = 0.f;
  #pragma unroll
  for (int it = 0; it < 4; ++it) {
    int row = blockIdx.x * 16 + it * 4 + w;
    const float* lp = logits + (size_t)row * C_CLS;
    float4 x[4];
    #pragma unroll
    for (int t = 0; t < 4; ++t) x[t] = *(const float4*)(lp + lane * 4 + 256 * t);
    float m = NINF;
    #pragma unroll
    for (int t = 0; t < 4; ++t)
      m = fmaxf(m, fmaxf(fmaxf(x[t].x, x[t].y), fmaxf(x[t].z, x[t].w)));
    #pragma unroll
    for (int off = 32; off; off >>= 1) m = fmaxf(m, __shfl_xor(m, off));
    float s = 0.f;
    #pragma unroll
    for (int t = 0; t < 4; ++t)
      s += __expf(x[t].x - m) + __expf(x[t].y - m) +
           __expf(x[t].z - m) + __expf(x[t].w - m);
    #pragma unroll
    for (int off = 32; off; off >>= 1) s += __shfl_xor(s, off);
    if (lane == 0) ce_acc += m + __logf(s) - lp[tgt[row]];
  }
  if (lane == 0) red_a[w] = ce_acc;
  __syncthreads();
  if (tid == 0) atomicAdd(&accum[0], red_a[0] + red_a[1] + red_a[2] + red_a[3]);
  __syncthreads();   // publish sflag, protect red_a reuse

  // ---- last finisher of this i-tile: read final posw/negw (sc1), exact fp32 triplet ----
  if (sflag) {
    if (tid < TI) {
      lds_pos[tid] = __hip_atomic_load(&posw[i0 + tid],
                                       __ATOMIC_RELAXED, __HIP_MEMORY_SCOPE_AGENT);
      lds_neg[tid] = __hip_atomic_load(&negw[i0 + tid],
                                       __ATOMIC_RELAXED, __HIP_MEMORY_SCOPE_AGENT);
    }
    __syncthreads();
    float tsum = 0.f, tcnt = 0.f;
    for (int rr = 0; rr < 32; ++rr) {
      int il = w * 32 + rr;
      int i  = i0 + il;
      unsigned long long pp = lds_pos[il], np = lds_neg[il];
      unsigned pidx = ~(unsigned)pp;
      unsigned nidx = (unsigned)np;
      bool valid = (pp != 0ULL) && (np != ~0ULL) && (pidx != (unsigned)i);
      float dap = 0.f, dan = 0.f;
      if (valid && lane < 48) {
        float4 a4 = *(const float4*)(e + (size_t)i    * D_DIM + lane * 4);
        float4 p4 = *(const float4*)(e + (size_t)pidx * D_DIM + lane * 4);
        float4 n4 = *(const float4*)(e + (size_t)nidx * D_DIM + lane * 4);
        float d;
        d = a4.x - p4.x + EPS_T; dap += d * d;
        d = a4.y - p4.y + EPS_T; dap += d * d;
        d = a4.z - p4.z + EPS_T; dap += d * d;
        d = a4.w - p4.w + EPS_T; dap += d * d;
        d = a4.x - n4.x + EPS_T; dan += d * d;
        d = a4.y - n4.y + EPS_T; dan += d * d;
        d = a4.z - n4.z + EPS_T; dan += d * d;
        d = a4.w - n4.w + EPS_T; dan += d * d;
      }
      #pragma unroll
      for (int off = 32; off; off >>= 1) {
        dap += __shfl_xor(dap, off);
        dan += __shfl_xor(dan, off);
      }
      if (lane == 0 && valid) {
        tsum += fmaxf(sqrtf(dap) - sqrtf(dan) + MARGIN, 0.f);
        tcnt += 1.f;
      }
    }
    if (lane == 0) { red_a[w] = tsum; red_b[w] = tcnt; }
    __syncthreads();
    if (tid == 0) {
      atomicAdd(&accum[1], red_a[0] + red_a[1] + red_a[2] + red_a[3]);
      atomicAdd(&accum[2], red_b[0] + red_b[1] + red_b[2] + red_b[3]);
    }
  }

  // ---- global finalize: last of NBLK blocks writes out ----
  __syncthreads();   // drains this block's accum adds (vmcnt) before elect
  if (tid == 0) {
    unsigned old = atomicAdd((unsigned*)&accum[3], 1u);
    if (old == NBLK - 1) {
      float cls = __hip_atomic_load(&accum[0], __ATOMIC_RELAXED, __HIP_MEMORY_SCOPE_AGENT);
      float ts  = __hip_atomic_load(&accum[1], __ATOMIC_RELAXED, __HIP_MEMORY_SCOPE_AGENT);
      float tc  = __hip_atomic_load(&accum[2], __ATOMIC_RELAXED, __HIP_MEMORY_SCOPE_AGENT);
      float trip = (tc > 0.f) ? ts / fmaxf(tc, 1.f) : 0.f;
      out[0] = cls / (float)B_N + trip;
    }
  }
}

extern "C" void kernel_launch(void* const* d_in, const int* in_sizes, int n_in,
                              void* d_out, int out_size, void* d_ws, size_t ws_size,
                              hipStream_t stream) {
  const float* emb    = (const float*)d_in[0];
  const float* logits = (const float*)d_in[1];
  const int*   tgt    = (const int*)d_in[2];
  float* out = (float*)d_out;

  char* ws = (char*)d_ws;
  unsigned short* ebf = (unsigned short*)ws;                        // 3,145,728 B
  float* sq = (float*)(ws + 3145728);                               // 32,768 B
  unsigned long long* posw = (unsigned long long*)(ws + 3178496);   // 65,536 B
  unsigned long long* negw = (unsigned long long*)(ws + 3244032);   // 65,536 B
  unsigned* tileCnt = (unsigned*)(ws + 3309568);                    // 256 B
  float* accum = (float*)(ws + 3309824);                            // 16 B: cls,tsum,tcnt,counter

  prep_kernel<<<NBLK, NTHR, 0, stream>>>(emb, ebf, sq, posw, negw, tileCnt, accum);
  mine_kernel<<<NBLK, NTHR, 0, stream>>>(ebf, tgt, sq, logits, emb,
                                         posw, negw, tileCnt, accum, out);
}